// Round 1
// baseline (1756.941 us; speedup 1.0000x reference)
//
#include <hip/hip_runtime.h>
#include <math.h>

#define DIM 64
#define NHEAD 16
#define DPH 4

__device__ __forceinline__ float waveReduceSum(float v) {
    #pragma unroll
    for (int off = 1; off < 64; off <<= 1)
        v += __shfl_xor(v, off, 64);
    return v;
}

// One wave (64 lanes) per node: LayerNorm -> qkv -> split q/k/v,
// input_dot from node_vec @ vec_w, and zero m_agg.
__global__ void node_kernel(const float* __restrict__ node_feat,
                            const float* __restrict__ node_vec,
                            const float* __restrict__ ln_g,
                            const float* __restrict__ ln_b,
                            const float* __restrict__ qkv_w,   // (64,192)
                            const float* __restrict__ qkv_b,   // (192,)
                            const float* __restrict__ vec_w,   // (64,128)
                            float* __restrict__ q,             // (N,64)
                            float* __restrict__ k,
                            float* __restrict__ v,
                            float* __restrict__ input_dot,     // (N,64)
                            float* __restrict__ m_agg,         // (N,64) zeroed here
                            int N)
{
    __shared__ float xs[4][DIM];
    __shared__ float nvs[4][3 * DIM];
    const int wave = threadIdx.x >> 6;
    const int lane = threadIdx.x & 63;
    const int n = blockIdx.x * 4 + wave;
    if (n >= N) return;

    // ---- LayerNorm ----
    float nf = node_feat[(size_t)n * DIM + lane];
    float mu = waveReduceSum(nf) * (1.0f / 64.0f);
    float d0 = nf - mu;
    float var = waveReduceSum(d0 * d0) * (1.0f / 64.0f);
    float x = d0 * rsqrtf(var + 1e-5f) * ln_g[lane] + ln_b[lane];
    xs[wave][lane] = x;

    // stage node_vec rows (3 x 64) for broadcast reads
    #pragma unroll
    for (int s = 0; s < 3; ++s)
        nvs[wave][s * DIM + lane] = node_vec[(size_t)n * 3 * DIM + s * DIM + lane];
    // intra-wave LDS write->read: in-order LDS pipe, no block barrier needed

    // ---- qkv = x @ qkv_w + qkv_b : lane j computes cols j, j+64, j+128 ----
    float acc0 = qkv_b[lane];
    float acc1 = qkv_b[lane + 64];
    float acc2 = qkv_b[lane + 128];
    for (int d = 0; d < DIM; ++d) {
        float xv = xs[wave][d];
        const float* wrow = qkv_w + d * 192;
        acc0 = fmaf(xv, wrow[lane], acc0);
        acc1 = fmaf(xv, wrow[lane + 64], acc1);
        acc2 = fmaf(xv, wrow[lane + 128], acc2);
    }
    // scatter columns into q/k/v (layout: col c = h*12 + t; t<4 q, <8 k, <12 v)
    {
        int cols[3] = { lane, lane + 64, lane + 128 };
        float vals[3] = { acc0, acc1, acc2 };
        #pragma unroll
        for (int i = 0; i < 3; ++i) {
            int c = cols[i];
            int h = c / 12, t = c % 12;
            float* dst = (t < 4) ? (q + (size_t)n * DIM + h * 4 + t)
                       : (t < 8) ? (k + (size_t)n * DIM + h * 4 + (t - 4))
                                 : (v + (size_t)n * DIM + h * 4 + (t - 8));
            *dst = vals[i];
        }
    }

    // ---- input_dot: iv = node_vec @ vec_w (N,3,128); dot over the 3 axis ----
    float a0[3] = {0.f, 0.f, 0.f};
    float a1[3] = {0.f, 0.f, 0.f};
    for (int d = 0; d < DIM; ++d) {
        float w0 = vec_w[d * 128 + lane];
        float w1 = vec_w[d * 128 + lane + 64];
        #pragma unroll
        for (int s = 0; s < 3; ++s) {
            float nv = nvs[wave][s * DIM + d];
            a0[s] = fmaf(nv, w0, a0[s]);
            a1[s] = fmaf(nv, w1, a1[s]);
        }
    }
    input_dot[(size_t)n * DIM + lane] = a0[0] * a1[0] + a0[1] * a1[1] + a0[2] * a1[2];
    m_agg[(size_t)n * DIM + lane] = 0.0f;
}

// One wave per edge: 16 head dots (4-lane shfl reduce), exact GELU, radial
// gate, message = v[col]*edge_feat*attn, atomic scatter-add into m_agg[row].
__global__ void edge_kernel(const float* __restrict__ q,
                            const float* __restrict__ k,
                            const float* __restrict__ v,
                            const float* __restrict__ edge_feat, // (E,16,4)=(E,64)
                            const float* __restrict__ radial,
                            const int* __restrict__ row,
                            const int* __restrict__ col,
                            float* __restrict__ m_agg,
                            int E)
{
    const int wave = threadIdx.x >> 6;
    const int lane = threadIdx.x & 63;
    const int e = blockIdx.x * 4 + wave;
    if (e >= E) return;

    const int r = row[e];
    const int c = col[e];

    float qd = q[(size_t)r * DIM + lane];
    float kd = k[(size_t)c * DIM + lane];
    float p = qd * kd;
    p += __shfl_xor(p, 1, 64);
    p += __shfl_xor(p, 2, 64);   // all 4 lanes of a head now hold the dot

    // exact GELU: 0.5*x*(1+erf(x/sqrt(2)))
    float g = 0.5f * p * (1.0f + erff(p * 0.70710678118654752f));
    float a = g * radial[e];

    float m = v[(size_t)c * DIM + lane] * edge_feat[(size_t)e * DIM + lane] * a;
    atomicAdd(&m_agg[(size_t)r * DIM + lane], m);
}

// One wave per node: out = m_agg @ out_w + out_b; result = idot*out[:64]+out[64:]
__global__ void out_kernel(const float* __restrict__ m_agg,
                           const float* __restrict__ input_dot,
                           const float* __restrict__ out_w,   // (64,128)
                           const float* __restrict__ out_b,   // (128,)
                           float* __restrict__ result,        // (N,64)
                           int N)
{
    __shared__ float ms[4][DIM];
    const int wave = threadIdx.x >> 6;
    const int lane = threadIdx.x & 63;
    const int n = blockIdx.x * 4 + wave;
    if (n >= N) return;

    ms[wave][lane] = m_agg[(size_t)n * DIM + lane];

    float o0 = out_b[lane];
    float o1 = out_b[lane + 64];
    for (int d = 0; d < DIM; ++d) {
        float mv = ms[wave][d];
        o0 = fmaf(mv, out_w[d * 128 + lane], o0);
        o1 = fmaf(mv, out_w[d * 128 + lane + 64], o1);
    }
    result[(size_t)n * DIM + lane] =
        input_dot[(size_t)n * DIM + lane] * o0 + o1;
}

extern "C" void kernel_launch(void* const* d_in, const int* in_sizes, int n_in,
                              void* d_out, int out_size, void* d_ws, size_t ws_size,
                              hipStream_t stream)
{
    const float* node_feat = (const float*)d_in[0];
    const float* edge_feat = (const float*)d_in[1];
    const float* node_vec  = (const float*)d_in[2];
    const float* radial    = (const float*)d_in[3];
    const float* ln_g      = (const float*)d_in[4];
    const float* ln_b      = (const float*)d_in[5];
    const float* qkv_w     = (const float*)d_in[6];
    const float* qkv_b     = (const float*)d_in[7];
    const float* vec_w     = (const float*)d_in[8];
    const float* out_w     = (const float*)d_in[9];
    const float* out_b     = (const float*)d_in[10];
    const int*   row       = (const int*)d_in[11];
    const int*   col       = (const int*)d_in[12];

    const int N = in_sizes[0] / DIM;   // 50000
    const int E = in_sizes[3];         // 1250000

    // workspace layout: q | k | v | input_dot | m_agg  (5 * N * 64 floats = 64 MB)
    float* ws     = (float*)d_ws;
    float* q      = ws;
    float* k      = q + (size_t)N * DIM;
    float* v      = k + (size_t)N * DIM;
    float* idot   = v + (size_t)N * DIM;
    float* m_agg  = idot + (size_t)N * DIM;

    const int nblk = (N + 3) / 4;
    const int eblk = (E + 3) / 4;

    node_kernel<<<nblk, 256, 0, stream>>>(node_feat, node_vec, ln_g, ln_b,
                                          qkv_w, qkv_b, vec_w,
                                          q, k, v, idot, m_agg, N);
    edge_kernel<<<eblk, 256, 0, stream>>>(q, k, v, edge_feat, radial,
                                          row, col, m_agg, E);
    out_kernel<<<nblk, 256, 0, stream>>>(m_agg, idot, out_w, out_b,
                                         (float*)d_out, N);
}

// Round 2
// 858.961 us; speedup vs baseline: 2.0454x; 2.0454x over previous
//
#include <hip/hip_runtime.h>
#include <math.h>

#define DIM 64
#define NW 4            // waves per block
#define NPB 4           // nodes per wave per iteration

__device__ __forceinline__ float waveReduceSum(float v) {
    #pragma unroll
    for (int off = 1; off < 64; off <<= 1)
        v += __shfl_xor(v, off, 64);
    return v;
}

// ---------------- Kernel A: LayerNorm + QKV projection ----------------
// qkv_w staged in LDS with columns PERMUTED to [q(64)|k(64)|v(64)] order so
// stores are lane-coalesced. 4 nodes per wave amortize LDS weight reads.
__global__ __launch_bounds__(256) void qkv_kernel(
    const float* __restrict__ node_feat,
    const float* __restrict__ ln_g, const float* __restrict__ ln_b,
    const float* __restrict__ qkv_w, const float* __restrict__ qkv_b,
    float* __restrict__ q, float* __restrict__ k, float* __restrict__ v,
    int N)
{
    __shared__ float  wlds[64 * 192];        // [d][j_permuted]  48 KB
    __shared__ float4 xs[NW][NPB][16];       // per-wave x rows   4 KB
    const int wave = threadIdx.x >> 6, lane = threadIdx.x & 63;

    // stage weights, permuting columns: target j -> source c
    for (int idx = threadIdx.x; idx < 64 * 192; idx += 256) {
        int d = idx / 192, j = idx - d * 192;
        int jj = j & 63, sec = j >> 6;                 // sec: 0=q 1=k 2=v
        int c = 12 * (jj >> 2) + (jj & 3) + 4 * sec;   // h*12 + t + 4*sec
        wlds[idx] = qkv_w[d * 192 + c];
    }
    const int c0 = 12 * (lane >> 2) + (lane & 3);
    const float b0 = qkv_b[c0], b1 = qkv_b[c0 + 4], b2 = qkv_b[c0 + 8];
    const float gg = ln_g[lane], bb = ln_b[lane];
    __syncthreads();

    const int nstride = gridDim.x * NW * NPB;
    for (int n0 = (blockIdx.x * NW + wave) * NPB; n0 < N; n0 += nstride) {
        const int cnt = min(NPB, N - n0);
        float acc0[NPB], acc1[NPB], acc2[NPB];
        #pragma unroll
        for (int i = 0; i < NPB; ++i) {
            acc0[i] = b0; acc1[i] = b1; acc2[i] = b2;
            if (i < cnt) {
                float nf = node_feat[(size_t)(n0 + i) * DIM + lane];
                float mu = waveReduceSum(nf) * (1.0f / 64.0f);
                float dv = nf - mu;
                float var = waveReduceSum(dv * dv) * (1.0f / 64.0f);
                float x = dv * rsqrtf(var + 1e-5f) * gg + bb;
                ((float*)&xs[wave][i][0])[lane] = x;   // same-wave LDS, in-order
            }
        }
        #pragma unroll 4
        for (int d4 = 0; d4 < 16; ++d4) {
            float4 xv[NPB];
            #pragma unroll
            for (int i = 0; i < NPB; ++i) xv[i] = xs[wave][i][d4];  // broadcast
            #pragma unroll
            for (int u = 0; u < 4; ++u) {
                int d = d4 * 4 + u;
                float w0 = wlds[d * 192 + lane];
                float w1 = wlds[d * 192 + lane + 64];
                float w2 = wlds[d * 192 + lane + 128];
                #pragma unroll
                for (int i = 0; i < NPB; ++i) {
                    float xd = (&xv[i].x)[u];
                    acc0[i] = fmaf(xd, w0, acc0[i]);
                    acc1[i] = fmaf(xd, w1, acc1[i]);
                    acc2[i] = fmaf(xd, w2, acc2[i]);
                }
            }
        }
        #pragma unroll
        for (int i = 0; i < NPB; ++i) if (i < cnt) {
            size_t off = (size_t)(n0 + i) * DIM + lane;
            q[off] = acc0[i]; k[off] = acc1[i]; v[off] = acc2[i];
        }
    }
}

// ---------------- Kernel B: input_dot (+ zero m_agg) ----------------
__global__ __launch_bounds__(256) void vec_kernel(
    const float* __restrict__ node_vec,
    const float* __restrict__ vec_w,
    float* __restrict__ input_dot,
    float* __restrict__ m_agg,
    int N)
{
    __shared__ float  vlds[64 * 128];          // 32 KB
    __shared__ float4 nvs[NW][NPB][3][16];     // 12 KB
    const int wave = threadIdx.x >> 6, lane = threadIdx.x & 63;

    for (int idx = threadIdx.x; idx < 64 * 128; idx += 256)
        vlds[idx] = vec_w[idx];
    __syncthreads();

    const int nstride = gridDim.x * NW * NPB;
    for (int n0 = (blockIdx.x * NW + wave) * NPB; n0 < N; n0 += nstride) {
        const int cnt = min(NPB, N - n0);
        float a0[NPB][3], a1[NPB][3];
        #pragma unroll
        for (int i = 0; i < NPB; ++i) {
            #pragma unroll
            for (int s = 0; s < 3; ++s) {
                a0[i][s] = 0.f; a1[i][s] = 0.f;
                if (i < cnt)
                    ((float*)&nvs[wave][i][s][0])[lane] =
                        node_vec[((size_t)(n0 + i) * 3 + s) * DIM + lane];
            }
        }
        #pragma unroll 2
        for (int d4 = 0; d4 < 16; ++d4) {
            #pragma unroll
            for (int u = 0; u < 4; ++u) {
                int d = d4 * 4 + u;
                float w0 = vlds[d * 128 + lane];
                float w1 = vlds[d * 128 + lane + 64];
                #pragma unroll
                for (int i = 0; i < NPB; ++i) {
                    #pragma unroll
                    for (int s = 0; s < 3; ++s) {
                        float nv = ((float*)&nvs[wave][i][s][d4])[u];
                        a0[i][s] = fmaf(nv, w0, a0[i][s]);
                        a1[i][s] = fmaf(nv, w1, a1[i][s]);
                    }
                }
            }
        }
        #pragma unroll
        for (int i = 0; i < NPB; ++i) if (i < cnt) {
            size_t off = (size_t)(n0 + i) * DIM + lane;
            input_dot[off] = a0[i][0] * a1[i][0] + a0[i][1] * a1[i][1]
                           + a0[i][2] * a1[i][2];
            m_agg[off] = 0.0f;
        }
    }
}

// ---------------- Kernel C: per-edge attention + scatter ----------------
__global__ __launch_bounds__(256) void edge_kernel(
    const float* __restrict__ q,
    const float* __restrict__ k,
    const float* __restrict__ v,
    const float* __restrict__ edge_feat, // (E,64)
    const float* __restrict__ radial,
    const int* __restrict__ row,
    const int* __restrict__ col,
    float* __restrict__ m_agg,
    int E)
{
    const int wave = threadIdx.x >> 6, lane = threadIdx.x & 63;
    const int e = blockIdx.x * NW + wave;
    if (e >= E) return;

    const int r = row[e];
    const int c = col[e];

    float qd = q[(size_t)r * DIM + lane];
    float kd = k[(size_t)c * DIM + lane];
    float p = qd * kd;
    p += __shfl_xor(p, 1, 64);
    p += __shfl_xor(p, 2, 64);   // head dot in all 4 lanes of the head

    float g = 0.5f * p * (1.0f + erff(p * 0.70710678118654752f));
    float a = g * radial[e];

    // edge_feat streams once (320 MB): nontemporal keeps it out of L2 so the
    // q/k/v gather set (38 MB) stays cache-resident
    float ef = __builtin_nontemporal_load(&edge_feat[(size_t)e * DIM + lane]);
    float m = v[(size_t)c * DIM + lane] * ef * a;
    atomicAdd(&m_agg[(size_t)r * DIM + lane], m);
}

// ---------------- Kernel D: output projection + epilogue ----------------
__global__ __launch_bounds__(256) void out_kernel(
    const float* __restrict__ m_agg,
    const float* __restrict__ input_dot,
    const float* __restrict__ out_w,   // (64,128)
    const float* __restrict__ out_b,   // (128,)
    float* __restrict__ result,        // (N,64)
    int N)
{
    __shared__ float  olds[64 * 128];      // 32 KB
    __shared__ float4 ms[NW][NPB][16];     // 4 KB
    const int wave = threadIdx.x >> 6, lane = threadIdx.x & 63;

    for (int idx = threadIdx.x; idx < 64 * 128; idx += 256)
        olds[idx] = out_w[idx];
    const float ob0 = out_b[lane], ob1 = out_b[lane + 64];
    __syncthreads();

    const int nstride = gridDim.x * NW * NPB;
    for (int n0 = (blockIdx.x * NW + wave) * NPB; n0 < N; n0 += nstride) {
        const int cnt = min(NPB, N - n0);
        float o0[NPB], o1[NPB];
        #pragma unroll
        for (int i = 0; i < NPB; ++i) {
            o0[i] = ob0; o1[i] = ob1;
            if (i < cnt)
                ((float*)&ms[wave][i][0])[lane] =
                    m_agg[(size_t)(n0 + i) * DIM + lane];
        }
        #pragma unroll 4
        for (int d4 = 0; d4 < 16; ++d4) {
            float4 mv[NPB];
            #pragma unroll
            for (int i = 0; i < NPB; ++i) mv[i] = ms[wave][i][d4];
            #pragma unroll
            for (int u = 0; u < 4; ++u) {
                int d = d4 * 4 + u;
                float w0 = olds[d * 128 + lane];
                float w1 = olds[d * 128 + lane + 64];
                #pragma unroll
                for (int i = 0; i < NPB; ++i) {
                    float md = (&mv[i].x)[u];
                    o0[i] = fmaf(md, w0, o0[i]);
                    o1[i] = fmaf(md, w1, o1[i]);
                }
            }
        }
        #pragma unroll
        for (int i = 0; i < NPB; ++i) if (i < cnt) {
            size_t off = (size_t)(n0 + i) * DIM + lane;
            result[off] = input_dot[off] * o0[i] + o1[i];
        }
    }
}

extern "C" void kernel_launch(void* const* d_in, const int* in_sizes, int n_in,
                              void* d_out, int out_size, void* d_ws, size_t ws_size,
                              hipStream_t stream)
{
    const float* node_feat = (const float*)d_in[0];
    const float* edge_feat = (const float*)d_in[1];
    const float* node_vec  = (const float*)d_in[2];
    const float* radial    = (const float*)d_in[3];
    const float* ln_g      = (const float*)d_in[4];
    const float* ln_b      = (const float*)d_in[5];
    const float* qkv_w     = (const float*)d_in[6];
    const float* qkv_b     = (const float*)d_in[7];
    const float* vec_w     = (const float*)d_in[8];
    const float* out_w     = (const float*)d_in[9];
    const float* out_b     = (const float*)d_in[10];
    const int*   row       = (const int*)d_in[11];
    const int*   col       = (const int*)d_in[12];

    const int N = in_sizes[0] / DIM;   // 50000
    const int E = in_sizes[3];         // 1250000

    float* ws    = (float*)d_ws;
    float* q     = ws;
    float* k     = q    + (size_t)N * DIM;
    float* v     = k    + (size_t)N * DIM;
    float* idot  = v    + (size_t)N * DIM;
    float* m_agg = idot + (size_t)N * DIM;

    const int grid_nodes = 768;             // ~3 blocks/CU co-resident
    const int eblk = (E + NW - 1) / NW;

    qkv_kernel<<<grid_nodes, 256, 0, stream>>>(node_feat, ln_g, ln_b,
                                               qkv_w, qkv_b, q, k, v, N);
    vec_kernel<<<grid_nodes, 256, 0, stream>>>(node_vec, vec_w, idot, m_agg, N);
    edge_kernel<<<eblk, 256, 0, stream>>>(q, k, v, edge_feat, radial,
                                          row, col, m_agg, E);
    out_kernel<<<grid_nodes, 256, 0, stream>>>(m_agg, idot, out_w, out_b,
                                               (float*)d_out, N);
}